// Round 8
// baseline (442.642 us; speedup 1.0000x reference)
//
#include <hip/hip_runtime.h>
#include <math.h>

// ExpertGate — np.einsum-bitwise replication; LDS-traffic-minimized version.
//
// CORRECTNESS CONTRACT (passed R2/R3/R5/R7): per (token, expert):
//   - 4 accumulator chains (k mod 4), packed as v2f components (per-component
//     VOP3P rounding == scalar); k in groups of 16 ASCENDING; quads within a
//     group processed j = 3,2,1,0; mul/add separately rounded, never fused
//     (#pragma clang fp contract(off); pk ops are inline asm = immune)
//   - final reduce (c0+c1)+(c2+c3); sigmoid 1/(1+exp(-z)) fp32 with
//     correctly-rounded fp32 exp (via double); top-8 ties -> lower index
//
// R7 POST-MORTEM: kernel is LDS-READ-THROUGHPUT-BOUND (~123us of DS time at
// 96 b128 reads/thread/round; measured 162-167us across R2/R7; occupancy, T14
// and pk-math all neutral because none cut DS bytes). THIS ROUND:
//   - per-thread tile 2x4 -> 4 tok x 4 exp (128-thr blocks, TM=32, grid 512,
//     2 blocks/CU): 1.5x fewer LDS reads per FLOP
//   - X moved OFF LDS: read global->reg, 16-lane-broadcast coalesced,
//     L1/L2-resident tile; DS pipe now carries W only (~41us chip-wide)
//   - W staged per 256-k mega-round (66.5KB LDS, 16 barriers total);
//     staging is coalesced global + conflict-free ds_write (row = lane)

#pragma clang fp contract(off)

#define D_DIM 2048
#define E_DIM 64
#define TOPK 8
#define TM 32               // tokens per block
#define MRK 256             // k per mega-round
#define NMR (D_DIM / MRK)   // 8 mega-rounds
#define NG  (MRK / 16)      // 16 groups of 16 k per mega-round
#define WS  260             // W LDS row stride (floats): 65 quads -> 2-way max
#define SCS 65

typedef float v2f __attribute__((ext_vector_type(2)));

static __device__ __forceinline__ v2f pk_mul(v2f a, v2f b) {
    v2f d;
    asm("v_pk_mul_f32 %0, %1, %2" : "=v"(d) : "v"(a), "v"(b));
    return d;
}
static __device__ __forceinline__ v2f pk_add(v2f a, v2f b) {
    v2f d;
    asm("v_pk_add_f32 %0, %1, %2" : "=v"(d) : "v"(a), "v"(b));
    return d;
}

// one 16-k group for all 16 (token i, expert e) pairs; X from registers,
// W from LDS. j = 3,2,1,0 per the contract.
#define GROUP_COMPUTE(g, XR)                                                   \
    {                                                                          \
        float4 wq[4][4];                                                       \
        _Pragma("unroll")                                                      \
        for (int e = 0; e < 4; ++e)                                            \
            _Pragma("unroll")                                                  \
            for (int j = 0; j < 4; ++j)                                        \
                wq[e][j] = *reinterpret_cast<const float4*>(                   \
                    &Wl[(tx + 16 * e) * WS + (g) * 16 + 4 * j]);               \
        _Pragma("unroll")                                                      \
        for (int j = 3; j >= 0; --j) {                                         \
            _Pragma("unroll")                                                  \
            for (int i = 0; i < 4; ++i) {                                      \
                const v2f xlo = *reinterpret_cast<const v2f*>(&XR[i][j].x);    \
                const v2f xhi = *reinterpret_cast<const v2f*>(&XR[i][j].z);    \
                _Pragma("unroll")                                              \
                for (int e = 0; e < 4; ++e) {                                  \
                    const v2f wlo = *reinterpret_cast<const v2f*>(&wq[e][j].x);\
                    const v2f whi = *reinterpret_cast<const v2f*>(&wq[e][j].z);\
                    c01[i][e] = pk_add(c01[i][e], pk_mul(xlo, wlo));           \
                    c23[i][e] = pk_add(c23[i][e], pk_mul(xhi, whi));           \
                }                                                              \
            }                                                                  \
        }                                                                      \
    }

#define X_LOAD(XR)                                                             \
    {                                                                          \
        _Pragma("unroll")                                                      \
        for (int i = 0; i < 4; ++i) {                                          \
            _Pragma("unroll")                                                  \
            for (int j = 0; j < 4; ++j)                                        \
                XR[i][j] = *reinterpret_cast<const float4*>(xp[i] + 4 * j);    \
            xp[i] += 16;                                                       \
        }                                                                      \
    }

__global__ __launch_bounds__(128, 1) void expert_gate_kernel(
    const float* __restrict__ x,      // (N, 2048)
    const float* __restrict__ w,      // (64, 2048)
    const float* __restrict__ bias,   // (64,)
    float* __restrict__ out,          // N*8 weights, then N*8 indices-as-float
    int N)
{
#pragma clang fp contract(off)
    __shared__ float Wl[E_DIM * WS];  // 66.6 KB
    __shared__ float Sc[TM * SCS];    //  8.3 KB   (74.9 KB -> 2 blocks/CU)

    const int t    = threadIdx.x;     // 0..127
    const int tx   = t & 15;          // experts tx + 16e
    const int ty   = t >> 4;          // 0..7; tokens ty + 8i
    const int tok0 = blockIdx.x * TM;
    const int lane = t & 63;
    const float my_bias = bias[lane];

    // ---- X row pointers (4 tokens per thread), advanced 16 floats/group ----
    const float* xp[4];
    #pragma unroll
    for (int i = 0; i < 4; ++i)
        xp[i] = &x[(size_t)(tok0 + ty + 8 * i) * D_DIM];

    // ---- W staging map: col = 4*lane (coalesced global, conflict-free LDS);
    //      rows h+2u, h = t>>6 (wave 0: even rows, wave 1: odd rows) ----
    const int h = t >> 6;
    const float* wsg = &w[(size_t)h * D_DIM + 4 * lane];
    float*       wsl = &Wl[h * WS + 4 * lane];

    // acc: c01[i][e]=(chain0,chain1), c23[i][e]=(chain2,chain3)
    v2f c01[4][4], c23[4][4];
    #pragma unroll
    for (int i = 0; i < 4; ++i)
        #pragma unroll
        for (int e = 0; e < 4; ++e) { c01[i][e] = (v2f)(0.f); c23[i][e] = (v2f)(0.f); }

    float4 XA[4][4], XB[4][4];
    X_LOAD(XA);                        // group 0

    for (int m = 0; m < NMR; ++m) {
        __syncthreads();               // prev mega-round's Wl readers done
        // ---- stage W chunk m: 64 rows x 256 k; 32 float4/thread ----
        {
            const float* gsrc = wsg + (size_t)m * MRK;
            #pragma unroll
            for (int b = 0; b < 4; ++b) {
                float4 tmp[8];
                #pragma unroll
                for (int u = 0; u < 8; ++u)
                    tmp[u] = *reinterpret_cast<const float4*>(
                        gsrc + (size_t)(b * 16 + 2 * u) * D_DIM);
                #pragma unroll
                for (int u = 0; u < 8; ++u)
                    *reinterpret_cast<float4*>(&wsl[(b * 16 + 2 * u) * WS]) = tmp[u];
            }
        }
        __syncthreads();

        // ---- 16 groups, ping-pong X registers (static indexing only) ----
        for (int gp = 0; gp < NG / 2; ++gp) {
            const int g0 = 2 * gp, g1 = 2 * gp + 1;
            // even group: prefetch XB (always exists: g1 in same mega-round)
            X_LOAD(XB);
            GROUP_COMPUTE(g0, XA);
            // odd group: prefetch XA for the next group (skip at very end)
            if (!(m == NMR - 1 && gp == NG / 2 - 1)) { X_LOAD(XA); }
            GROUP_COMPUTE(g1, XB);
        }
    }

    // ---- finalize: (c0+c1)+(c2+c3), fp32 sigmoid exactly like np ----
    #pragma unroll
    for (int i = 0; i < 4; ++i) {
        #pragma unroll
        for (int e = 0; e < 4; ++e) {
            float z = __fadd_rn(__fadd_rn(c01[i][e].x, c01[i][e].y),
                                __fadd_rn(c23[i][e].x, c23[i][e].y));
            float ez = (float)exp(-(double)z);   // correctly-rounded fp32 exp
            float sg = __fdiv_rn(1.0f, __fadd_rn(1.0f, ez));
            Sc[(ty + 8 * i) * SCS + (tx + 16 * e)] = sg;
        }
    }
    __syncthreads();

    // ---- top-8 per token: lane == expert; 2 waves x 16 tokens ----
    const int wave = t >> 6;  // 0..1
    for (int r = 0; r < 16; ++r) {
        const int tok = wave * 16 + r;
        const float sg = Sc[tok * SCS + lane];   // original fp32 score
        float rv = __fadd_rn(sg, my_bias);       // routing score
        float outw = 0.f;
        int   outi = 0;
        float ssum = 0.f;
        #pragma unroll
        for (int sel = 0; sel < TOPK; ++sel) {
            float vv = rv;
            int   vi = lane;
            // 64-lane butterfly lexicographic max (ties -> lower index, = top_k)
            #pragma unroll
            for (int off = 1; off < 64; off <<= 1) {
                float ov = __shfl_xor(vv, off);
                int   oi = __shfl_xor(vi, off);
                if (ov > vv || (ov == vv && oi < vi)) { vv = ov; vi = oi; }
            }
            float cs = __shfl(sg, vi);  // un-biased score of winner
            ssum = __fadd_rn(ssum, cs);
            if (lane == sel) { outw = cs; outi = vi; }
            if (lane == vi) rv = -INFINITY;
        }
        if (lane < TOPK) {
            const size_t base = (size_t)(tok0 + tok) * TOPK + lane;
            out[base] = __fmul_rn(__fdiv_rn(outw, __fadd_rn(ssum, 1e-8f)), 2.5f);
            out[(size_t)N * TOPK + base] = (float)outi;
        }
    }
}

extern "C" void kernel_launch(void* const* d_in, const int* in_sizes, int n_in,
                              void* d_out, int out_size, void* d_ws, size_t ws_size,
                              hipStream_t stream) {
    const float* x    = (const float*)d_in[0];
    const float* w    = (const float*)d_in[1];
    const float* bias = (const float*)d_in[2];
    float* out = (float*)d_out;
    const int N = in_sizes[0] / D_DIM;  // 16384
    const int grid = N / TM;            // 512
    expert_gate_kernel<<<grid, 128, 0, stream>>>(x, w, bias, out, N);
}